// Round 2
// baseline (21892.792 us; speedup 1.0000x reference)
//
#include <hip/hip_runtime.h>
#include <hip/hip_bf16.h>
#include <stdint.h>
#include <math.h>

// ElmoLstm on MI355X — persistent-kernel version.
// L=2 layers x 2 dirs, B=64, T=128, D=H=512, C=4096.
// One persistent kernel (256 blocks = 1/CU) runs the whole recurrence with
// device-scope grid barriers (2 per step). c-state lives in registers.
// Weights converted fp32->bf16 once per call by small parallel kernels.

#define BB 64
#define TT 128
#define DD 512
#define HH 512
#define CC 4096
#define NBLK 256

typedef __bf16 v8bf __attribute__((ext_vector_type(8)));
typedef float  v4f  __attribute__((ext_vector_type(4)));
typedef short  v8s  __attribute__((ext_vector_type(8)));

struct Bar { unsigned cnt[2]; unsigned gen; unsigned pad; };

__device__ __forceinline__ uint16_t f2bf(float f) {
    unsigned int x = __float_as_uint(f);
    unsigned int r = (x + 0x7fffu + ((x >> 16) & 1u)) >> 16;
    return (uint16_t)r;
}
__device__ __forceinline__ float sigm(float x) { return 1.0f / (1.0f + __expf(-x)); }

__device__ __forceinline__ void gbar(Bar* b, unsigned* lg) {
    __syncthreads();
    if (threadIdx.x == 0) {
        unsigned g = *lg;
        __builtin_amdgcn_fence(__ATOMIC_RELEASE, "agent");
        unsigned a = __hip_atomic_fetch_add(&b->cnt[g & 1], 1u,
                        __ATOMIC_ACQ_REL, __HIP_MEMORY_SCOPE_AGENT);
        if (a == NBLK - 1) {
            // all blocks arrived; recycle the counter used 2 barriers ago
            __hip_atomic_store(&b->cnt[(g + 1) & 1], 0u,
                               __ATOMIC_RELAXED, __HIP_MEMORY_SCOPE_AGENT);
            __hip_atomic_store(&b->gen, g + 1,
                               __ATOMIC_RELEASE, __HIP_MEMORY_SCOPE_AGENT);
        } else {
            while (__hip_atomic_load(&b->gen, __ATOMIC_RELAXED,
                                     __HIP_MEMORY_SCOPE_AGENT) == g)
                __builtin_amdgcn_s_sleep(2);
        }
        __builtin_amdgcn_fence(__ATOMIC_ACQUIRE, "agent");
    }
    *lg += 1;
    __syncthreads();
}

// ---------------- weight conversion ----------------
__global__ __launch_bounds__(256) void k_conv_wfull(
        const float* __restrict__ Wi, const float* __restrict__ Wh,
        uint16_t* __restrict__ Wf) {
    size_t i   = (size_t)blockIdx.x * blockDim.x + threadIdx.x;
    size_t idx = i * 8;
    size_t row = idx >> 10;
    int    k   = (int)(idx & 1023);
    const float* s = (k < 512) ? (Wh + row * 512 + k) : (Wi + row * 512 + (k - 512));
    float4 f0 = ((const float4*)s)[0];
    float4 f1 = ((const float4*)s)[1];
    v8s v;
    v[0]=f2bf(f0.x); v[1]=f2bf(f0.y); v[2]=f2bf(f0.z); v[3]=f2bf(f0.w);
    v[4]=f2bf(f1.x); v[5]=f2bf(f1.y); v[6]=f2bf(f1.z); v[7]=f2bf(f1.w);
    ((v8s*)Wf)[i] = v;
}

__global__ __launch_bounds__(256) void k_conv_plain(
        const float* __restrict__ src, uint16_t* __restrict__ dst, int n8) {
    int i = blockIdx.x * blockDim.x + threadIdx.x;
    if (i >= n8) return;
    const float4* s = (const float4*)(src + (size_t)i * 8);
    float4 f0 = s[0];
    float4 f1 = s[1];
    v8s v;
    v[0]=f2bf(f0.x); v[1]=f2bf(f0.y); v[2]=f2bf(f0.z); v[3]=f2bf(f0.w);
    v[4]=f2bf(f1.x); v[5]=f2bf(f1.y); v[6]=f2bf(f1.z); v[7]=f2bf(f1.w);
    ((v8s*)dst)[i] = v;
}

// ---------------- persistent recurrence kernel ----------------
// 256 blocks x 256 thr (4 waves). Per step:
//   gates phase: all 256 blocks (gdir = blk>>7, gbx = blk&127): 32 cells x
//     4 gates x 64 batch, K=1024 ([h|x]), MFMA 16x16x32 bf16; elementwise
//     LSTM cell with c in registers; act -> global bf16.
//   [grid barrier]
//   proj phase: blocks 0..63 (pdir = blk>>5, pnt = blk&31): 64m x 16n tile,
//     K=4096 split across 4 waves, LDS reduce, clip, write h/seq outputs.
//   [grid barrier]
__global__ __launch_bounds__(256) void k_persist(
        const uint16_t* __restrict__ Wf,   // [2][2][16384][1024] bf16
        const float*    __restrict__ bias, // [2][2][16384]
        const uint16_t* __restrict__ Wpb,  // [2][2][512][4096] bf16
        const uint16_t* __restrict__ xb,   // [64][128][512] bf16
        uint16_t* __restrict__ hseq,       // [2][64][128][512] bf16 (layer0 out)
        uint16_t* __restrict__ hb,         // [2][64][512] bf16
        uint16_t* __restrict__ actb,       // [2][64][4096] bf16
        float* __restrict__ out,           // full output buffer
        Bar* __restrict__ bar) {
    const int tid  = threadIdx.x;
    const int w    = tid >> 6;
    const int lane = tid & 63;
    const int col  = lane & 15;
    const int quad = lane >> 4;
    const int blk  = blockIdx.x;
    const int gdir = blk >> 7;      // gates role
    const int gbx  = blk & 127;

    const size_t SEQ = (size_t)BB * TT * 1024;
    float* hs_base = out + 2 * SEQ;
    float* cs_base = hs_base + 2ull * BB * 1024;

    unsigned lg = 0;
    float c_reg[8];
    __shared__ float gt[4][64][33];   // gates epilogue; proj reuses as red[]

    for (int l = 0; l < 2; ++l) {
        const uint16_t* Wl  = Wf + ((size_t)l * 2 + gdir) * 16384 * 1024;
        const float*    bd  = bias + ((size_t)l * 2 + gdir) * 16384;
        const uint16_t* Wpl = Wpb + (size_t)l * 2 * 512 * 4096;
        const uint16_t* xsrc = l ? (hseq + (size_t)gdir * BB * TT * HH) : xb;
        float* seq_l = out + (size_t)l * SEQ;
        float* cs_l  = cs_base + (size_t)l * BB * 8192;
        float* hs_l  = hs_base + (size_t)l * BB * 1024;

        for (int t = 0; t < TT; ++t) {
            const bool first = (t == 0), last = (t == TT - 1);
            const int tt = gdir ? (127 - t) : t;

            // ---------- gates ----------
            {
                const uint16_t* hp = hb + (size_t)gdir * BB * HH;
                const uint16_t* brow0 = Wl + (size_t)(w * 4096 + gbx * 32 + col) * 1024;
                const uint16_t* brow1 = brow0 + 16 * 1024;
                v4f acc[4][2] = {};
                int ks0 = first ? 16 : 0;   // h0 == 0: skip h half of K
                for (int ks = ks0; ks < 32; ++ks) {
                    int k = ks * 32 + quad * 8;
                    v8bf a[4], b0, b1;
                    if (k < 512) {
#pragma unroll
                        for (int mt = 0; mt < 4; ++mt)
                            a[mt] = *(const v8bf*)(hp + (size_t)(mt * 16 + col) * HH + k);
                    } else {
#pragma unroll
                        for (int mt = 0; mt < 4; ++mt)
                            a[mt] = *(const v8bf*)(xsrc + ((size_t)(mt * 16 + col) * TT + tt) * DD + (k - 512));
                    }
                    b0 = *(const v8bf*)(brow0 + k);
                    b1 = *(const v8bf*)(brow1 + k);
#pragma unroll
                    for (int mt = 0; mt < 4; ++mt) {
                        acc[mt][0] = __builtin_amdgcn_mfma_f32_16x16x32_bf16(a[mt], b0, acc[mt][0], 0, 0, 0);
                        acc[mt][1] = __builtin_amdgcn_mfma_f32_16x16x32_bf16(a[mt], b1, acc[mt][1], 0, 0, 0);
                    }
                }
#pragma unroll
                for (int mt = 0; mt < 4; ++mt)
#pragma unroll
                    for (int nt = 0; nt < 2; ++nt)
#pragma unroll
                        for (int r = 0; r < 4; ++r)
                            gt[w][mt * 16 + quad * 4 + r][nt * 16 + col] = acc[mt][nt][r];
                __syncthreads();

#pragma unroll
                for (int i = 0; i < 8; ++i) {
                    int idx  = i * 256 + tid;
                    int m    = idx >> 5;
                    int cl   = idx & 31;
                    int cell = gbx * 32 + cl;
                    float xi = gt[0][m][cl] + bd[cell];
                    float xf = gt[1][m][cl] + bd[4096 + cell];
                    float xg = gt[2][m][cl] + bd[8192 + cell];
                    float xo = gt[3][m][cl] + bd[12288 + cell];
                    float iv = sigm(xi), fv = sigm(xf), ov = sigm(xo);
                    float gv = tanhf(xg);
                    float cold = first ? 0.0f : c_reg[i];
                    float cn = fminf(fmaxf(iv * gv + fv * cold, -3.0f), 3.0f);
                    c_reg[i] = cn;
                    actb[((size_t)gdir * BB + m) * CC + cell] = f2bf(ov * tanhf(cn));
                    if (last) cs_l[(size_t)m * 8192 + gdir * 4096 + cell] = cn;
                }
            }
            gbar(bar, &lg);

            // ---------- proj ----------
            if (blk < 64) {
                const int pdir = blk >> 5;
                const int pnt  = blk & 31;
                const int ptt  = pdir ? (127 - t) : t;
                const uint16_t* Ad   = actb + (size_t)pdir * BB * CC;
                const uint16_t* Brow = Wpl + ((size_t)pdir * HH + pnt * 16 + col) * CC;
                v4f pacc[4] = {};
                for (int it = 0; it < 32; ++it) {
                    int k = w * 1024 + it * 32 + quad * 8;
                    v8bf bfr = *(const v8bf*)(Brow + k);
#pragma unroll
                    for (int mt = 0; mt < 4; ++mt) {
                        v8bf a = *(const v8bf*)(Ad + (size_t)(mt * 16 + col) * CC + k);
                        pacc[mt] = __builtin_amdgcn_mfma_f32_16x16x32_bf16(a, bfr, pacc[mt], 0, 0, 0);
                    }
                }
                float* red = (float*)gt;   // [4][4][16][16]
#pragma unroll
                for (int mt = 0; mt < 4; ++mt)
#pragma unroll
                    for (int r = 0; r < 4; ++r)
                        red[((w * 4 + mt) * 16 + quad * 4 + r) * 16 + col] = pacc[mt][r];
                __syncthreads();
#pragma unroll
                for (int i = 0; i < 4; ++i) {
                    int idx = i * 256 + tid;     // 1024 outputs: 64m x 16n
                    int m   = idx >> 4;
                    int nl  = idx & 15;
                    float s = red[((0 * 4 + (m >> 4)) * 16 + (m & 15)) * 16 + nl]
                            + red[((1 * 4 + (m >> 4)) * 16 + (m & 15)) * 16 + nl]
                            + red[((2 * 4 + (m >> 4)) * 16 + (m & 15)) * 16 + nl]
                            + red[((3 * 4 + (m >> 4)) * 16 + (m & 15)) * 16 + nl];
                    float h = fminf(fmaxf(s, -3.0f), 3.0f);
                    int n = pnt * 16 + nl;
                    uint16_t hbv = f2bf(h);
                    hb[((size_t)pdir * BB + m) * HH + n] = hbv;
                    if (l == 0)
                        hseq[(((size_t)pdir * BB + m) * TT + ptt) * HH + n] = hbv;
                    size_t so = ((size_t)m * TT + ptt) * 1024 + (size_t)pdir * 512 + n;
                    float outv = h;
                    if (l == 1) outv += out[so];   // residual from layer-0 seq
                    seq_l[so] = outv;
                    if (last) hs_l[(size_t)m * 1024 + pdir * 512 + n] = h;
                }
            }
            gbar(bar, &lg);
        }
    }
}

// ---------------- launch ----------------
extern "C" void kernel_launch(void* const* d_in, const int* in_sizes, int n_in,
                              void* d_out, int out_size, void* d_ws, size_t ws_size,
                              hipStream_t stream) {
    const float* x  = (const float*)d_in[0];
    const float* Wi = (const float*)d_in[1];
    const float* Wh = (const float*)d_in[2];
    const float* bb = (const float*)d_in[3];
    const float* Wp = (const float*)d_in[4];
    float* out = (float*)d_out;

    char* ws = (char*)d_ws;
    size_t off = 0;
    auto take = [&](size_t bytes) -> char* {
        char* p = ws + off;
        off = (off + bytes + 255) & ~(size_t)255;
        return p;
    };
    uint16_t* Wf   = (uint16_t*)take(2ull * 2 * 16384 * 1024 * 2); // 134 MB
    uint16_t* Wpb  = (uint16_t*)take(2ull * 2 * 512 * 4096 * 2);   // 16.8 MB
    uint16_t* xb   = (uint16_t*)take((size_t)BB * TT * DD * 2);    // 8.4 MB
    uint16_t* hseq = (uint16_t*)take(2ull * BB * TT * HH * 2);     // 16.8 MB
    uint16_t* hb   = (uint16_t*)take(2ull * BB * HH * 2);
    uint16_t* actb = (uint16_t*)take(2ull * BB * CC * 2);
    Bar*      bar  = (Bar*)take(256);

    hipMemsetAsync(bar, 0, 256, stream);
    hipLaunchKernelGGL(k_conv_wfull, dim3(32768), dim3(256), 0, stream, Wi, Wh, Wf);
    hipLaunchKernelGGL(k_conv_plain, dim3(4096), dim3(256), 0, stream, Wp, Wpb,
                       2 * 2 * 512 * 4096 / 8);
    hipLaunchKernelGGL(k_conv_plain, dim3(2048), dim3(256), 0, stream, x, xb,
                       BB * TT * DD / 8);
    hipLaunchKernelGGL(k_persist, dim3(NBLK), dim3(256), 0, stream,
                       Wf, bb, Wpb, xb, hseq, hb, actb, out, bar);
}